// Round 2
// baseline (9300.619 us; speedup 1.0000x reference)
//
#include <hip/hip_runtime.h>
#include <math.h>

#define BATCH  1024
#define SEQ    256
#define UNITS  256
#define NC     128
#define FOURU  1024
#define NBLK   256
#define NTHR   512

// ---------------------------------------------------------------------------
// Fast gate math. Precision budget: threshold 1.72e-4 absolute; fp32 chain
// currently at 6.1e-5. __expf -> v_exp_f32 (~1 ulp). tanh via 1 - 2/(1+e^2x).
__device__ __forceinline__ float sigf(float x)  { return 1.f / (1.f + __expf(-x)); }
__device__ __forceinline__ float tanhf_(float x){ return 1.f - 2.f / (1.f + __expf(2.f * x)); }

// ---------------------------------------------------------------------------
// Pre-pass: pack R[k][g*256+u] -> Rp[k][u*4+g] (so one wave's 8 columns are
// 8 contiguous floats = one s_load_dwordx8), zero h^T ping buffer, zero barrier.
__global__ __launch_bounds__(256) void prep(const float* __restrict__ R,
                                            float* __restrict__ Rp,
                                            float* __restrict__ hTA,
                                            unsigned* __restrict__ bar)
{
    int i = blockIdx.x * 256 + threadIdx.x;   // grid covers 262144
    int k = i >> 10;
    int r = i & 1023;
    int u = r >> 2;
    int g = r & 3;
    Rp[i]  = R[(k << 10) + (g << 8) + u];
    hTA[i] = 0.f;
    if (i == 0) *bar = 0u;
}

// ---------------------------------------------------------------------------
// Persistent LSTM: 256 blocks x 512 threads (8 waves/block, 2 waves/SIMD).
// Block = (batch-group bg of 64, unit-group ug of 16). Wave w owns units
// {u0, u0+1}, lanes = 64 batches. Per k: 1 coalesced h load (vector pipe) +
// 1 uniform 32B Rp load (scalar pipe) + 8 FMAs. c never leaves registers.
// One device-wide barrier per timestep (h ping-pong across blocks).
__global__ __launch_bounds__(NTHR) void lstm_persist(
    const float* __restrict__ Rp,    // [256][256][4] packed recurrent
    const float* __restrict__ Wk,    // [128][1024] original layout
    const float* __restrict__ bias,  // [1024]
    const int*   __restrict__ inp,   // [1024][256]
    float* __restrict__ hTA,         // [256][1024] h^T ping (zeroed)
    float* __restrict__ hTB,         // [256][1024] h^T pong
    unsigned* __restrict__ bar)      // barrier counter (zeroed)
{
    const int tid  = threadIdx.x;
    const int lane = tid & 63;
    const int wv   = tid >> 6;
    const int bg   = blockIdx.x & 15;
    const int ug   = blockIdx.x >> 4;
    const int u0   = __builtin_amdgcn_readfirstlane(ug * 16 + wv * 2);
    const int b    = bg * 64 + lane;

    // bias for my 8 columns (uniform -> scalar loads, hoisted out of t-loop)
    float bw[8];
#pragma unroll
    for (int g = 0; g < 4; g++) {
        bw[g]     = bias[(g << 8) + u0];
        bw[4 + g] = bias[(g << 8) + u0 + 1];
    }

    float c0 = 0.f, c1 = 0.f;
    const int binp = b * SEQ;

    for (int t = 0; t < SEQ; t++) {
        const float* hin  = (t & 1) ? hTB : hTA;
        float*       hout = (t & 1) ? hTA : hTB;

        // x-projection gather: issued up front, consumed after k-loop
        int ch = inp[binp + t];
        const float* wkr = Wk + ch * FOURU + u0;
        float2 w0 = *(const float2*)(wkr);
        float2 w1 = *(const float2*)(wkr + 256);
        float2 w2 = *(const float2*)(wkr + 512);
        float2 w3 = *(const float2*)(wkr + 768);

        float acc[8];
#pragma unroll
        for (int j = 0; j < 8; j++) acc[j] = 0.f;

        const float4* rp = (const float4*)(Rp + (u0 << 2)); // row k at rp[k*256]
        const float*  hp = hin + b;
#pragma unroll 4
        for (int k = 0; k < UNITS; k++) {
            float  hv = hp[k << 10];
            float4 r0 = rp[(k << 8)];
            float4 r1 = rp[(k << 8) + 1];
            acc[0] += hv * r0.x; acc[1] += hv * r0.y;
            acc[2] += hv * r0.z; acc[3] += hv * r0.w;
            acc[4] += hv * r1.x; acc[5] += hv * r1.y;
            acc[6] += hv * r1.z; acc[7] += hv * r1.w;
        }

        // gates (Keras order i, f, g, o)
        float i0 = sigf  (acc[0] + w0.x + bw[0]);
        float f0 = sigf  (acc[1] + w1.x + bw[1]);
        float g0 = tanhf_(acc[2] + w2.x + bw[2]);
        float o0 = sigf  (acc[3] + w3.x + bw[3]);
        c0 = f0 * c0 + i0 * g0;
        float h0v = o0 * tanhf_(c0);

        float i1 = sigf  (acc[4] + w0.y + bw[4]);
        float f1 = sigf  (acc[5] + w1.y + bw[5]);
        float g1 = tanhf_(acc[6] + w2.y + bw[6]);
        float o1 = sigf  (acc[7] + w3.y + bw[7]);
        c1 = f1 * c1 + i1 * g1;
        float h1v = o1 * tanhf_(c1);

        hout[(u0 << 10) + b]       = h0v;
        hout[((u0 + 1) << 10) + b] = h1v;

        // device-wide barrier (skip after last step; kernel end is a release)
        if (t != SEQ - 1) {
            __syncthreads();
            if (tid == 0) {
                __threadfence();                       // release: L2 writeback
                atomicAdd(bar, 1u);                    // device scope
                unsigned target = (unsigned)(t + 1) * NBLK;
                while (__hip_atomic_load(bar, __ATOMIC_RELAXED,
                                         __HIP_MEMORY_SCOPE_AGENT) < target)
                    __builtin_amdgcn_s_sleep(1);
                __threadfence();                       // acquire: L1/L2 inv
            }
            __syncthreads();
        }
    }
}

// ---------------------------------------------------------------------------
// logits = h_last @ dense_w + dense_b ; softmax. h arrives transposed [u][b].
__global__ __launch_bounds__(128) void dense_softmax(
    const float* __restrict__ hT,  // [256][1024]
    const float* __restrict__ W,   // [256][128]
    const float* __restrict__ b,   // [128]
    float*       __restrict__ out) // [1024][128]
{
    __shared__ float hsr[UNITS];
    __shared__ float red[NC];
    const int bq = blockIdx.x;
    const int n  = threadIdx.x;

    hsr[n]       = hT[(n << 10) + bq];
    hsr[n + 128] = hT[((n + 128) << 10) + bq];
    __syncthreads();

    float acc = b[n];
#pragma unroll 8
    for (int k = 0; k < UNITS; k++) acc += hsr[k] * W[k * NC + n];

    red[n] = acc;
    __syncthreads();
    for (int s = 64; s > 0; s >>= 1) {
        if (n < s) red[n] = fmaxf(red[n], red[n + s]);
        __syncthreads();
    }
    float m = red[0];
    __syncthreads();

    float e = __expf(acc - m);
    red[n] = e;
    __syncthreads();
    for (int s = 64; s > 0; s >>= 1) {
        if (n < s) red[n] = red[n] + red[n + s];
        __syncthreads();
    }
    out[bq * NC + n] = e / red[0];
}

// ---------------------------------------------------------------------------
extern "C" void kernel_launch(void* const* d_in, const int* in_sizes, int n_in,
                              void* d_out, int out_size, void* d_ws, size_t ws_size,
                              hipStream_t stream)
{
    const int*   inp  = (const int*)d_in[0];    // [1024][256]
    const float* Wk   = (const float*)d_in[1];  // [128][1024]
    const float* R    = (const float*)d_in[2];  // [256][1024]
    const float* bias = (const float*)d_in[3];  // [1024]
    const float* Wd   = (const float*)d_in[4];  // [256][128]
    const float* bd   = (const float*)d_in[5];  // [128]
    float* out = (float*)d_out;

    // ws layout (3 MB, same footprint as round-1): hTA | hTB | Rp
    float* hTA = (float*)d_ws;
    float* hTB = hTA + 262144;
    float* Rp  = hTB + 262144;
    // barrier counter lives in d_out's last element; dense_softmax overwrites
    // it at the end, so the validated output is untouched.
    unsigned* bar = (unsigned*)(out + BATCH * NC - 1);

    prep<<<dim3(1024), dim3(256), 0, stream>>>(R, Rp, hTA, bar);

    {
        void* args[] = { (void*)&Rp, (void*)&Wk, (void*)&bias, (void*)&inp,
                         (void*)&hTA, (void*)&hTB, (void*)&bar };
        hipLaunchCooperativeKernel((const void*)lstm_persist, dim3(NBLK), dim3(NTHR),
                                   args, 0, stream);
    }

    // t=255 (odd) wrote hTA
    dense_softmax<<<dim3(BATCH), dim3(128), 0, stream>>>(hTA, Wd, bd, out);
}

// Round 3
// 4303.153 us; speedup vs baseline: 2.1613x; 2.1613x over previous
//
#include <hip/hip_runtime.h>
#include <math.h>

#define BATCH  1024
#define SEQ    256
#define UNITS  256
#define NC     128
#define FOURU  1024

// Gate math (validated rounds 1-2: absmax 6.1e-5 vs 1.72e-4 threshold)
__device__ __forceinline__ float sigf(float x)  { return 1.f / (1.f + __expf(-x)); }
__device__ __forceinline__ float tanhf_(float x){ return 1.f - 2.f / (1.f + __expf(2.f * x)); }

// ---------------------------------------------------------------------------
// prep: pack Rp[k][u*4+g] = R[k][g*256+u]   (wave's 16 cols contiguous)
//       Wkb[ch][u*4+g] = Wk[ch][g*256+u] + bias[g*256+u]   (bias folded)
//       zero hTA (h_0 = 0) and cT (c_0 = 0)
__global__ __launch_bounds__(256) void prep(const float* __restrict__ R,
                                            const float* __restrict__ Wk,
                                            const float* __restrict__ bias,
                                            float* __restrict__ Rp,
                                            float* __restrict__ Wkb,
                                            float* __restrict__ hTA,
                                            float* __restrict__ cT)
{
    int i = blockIdx.x * 256 + threadIdx.x;     // 0..262143
    int r = i & 1023;
    int u = r >> 2;
    int g = r & 3;
    int src = (g << 8) + u;                      // original column g*256+u
    int row = i >> 10;
    Rp[i]  = R[(row << 10) + src];
    hTA[i] = 0.f;
    cT[i]  = 0.f;
    if (i < (NC << 10)) {                        // 128 rows of Wk
        Wkb[i] = Wk[(row << 10) + src] + bias[src];
    }
}

// ---------------------------------------------------------------------------
// One timestep. Grid 256 blocks x 256 thr. Block = 64 batches x 16 units
// (64 packed cols). Wave w owns units ug*16+4w..+3 -> 16 contiguous packed
// cols; lanes = 64 batches. Per k: 1 coalesced h load + 4 broadcast
// ds_read_b128 of R + 16 FMAs. h loads double-buffered 8 deep.
__global__ __launch_bounds__(256) void lstm_step(
    const float* __restrict__ hin,   // [256 k][1024 b]
    float*       __restrict__ hout,  // [256 u][1024 b]
    float*       __restrict__ cT,    // [256 u][1024 b]
    const float* __restrict__ Rp,    // [256 k][1024 col']
    const float* __restrict__ Wkb,   // [128 ch][1024 col']
    const int*   __restrict__ inp,   // [1024 b][256 t]
    int t)
{
    __shared__ float Rl[256 * 64];   // block's 64-col R slice, [k][64]

    const int tid  = threadIdx.x;
    const int lane = tid & 63;
    const int w    = tid >> 6;            // wave 0..3
    const int bg   = blockIdx.x & 15;     // batch group (x64)
    const int ug   = blockIdx.x >> 4;     // unit group (x16)
    const int b    = (bg << 6) + lane;

    // x-projection gather: 16 scattered dwords, issued before the barrier so
    // they overlap R staging + k-loop.
    const int ch = inp[b * SEQ + t];
    const float* wkr = Wkb + (ch << 10) + (ug << 6) + (w << 4);
    float4 wkA = *(const float4*)(wkr + 0);
    float4 wkB = *(const float4*)(wkr + 4);
    float4 wkC = *(const float4*)(wkr + 8);
    float4 wkD = *(const float4*)(wkr + 12);

    // Stage R slice: 256 rows x 64 cols = 64 KB. 16 passes, each pass 16 rows
    // x 16 threads x float4.
    {
        const float* src = Rp + (ug << 6);
        const int kk = tid >> 4;          // row within pass group
        const int cc = (tid & 15) << 2;   // col (x4)
#pragma unroll
        for (int p = 0; p < 16; p++) {
            int k = p * 16 + kk;
            *(float4*)&Rl[(k << 6) + cc] = *(const float4*)&src[(k << 10) + cc];
        }
    }
    __syncthreads();

    float acc[16];
#pragma unroll
    for (int j = 0; j < 16; j++) acc[j] = 0.f;

    const float* hp = hin + b;
    const float* rl = &Rl[w << 4];        // + k*64

    float hreg[8];
#pragma unroll
    for (int j = 0; j < 8; j++) hreg[j] = hp[j << 10];

    for (int kg = 0; kg < 32; kg++) {
        float hnxt[8];
        if (kg < 31) {
#pragma unroll
            for (int j = 0; j < 8; j++) hnxt[j] = hp[(((kg + 1) << 3) + j) << 10];
        }
#pragma unroll
        for (int j = 0; j < 8; j++) {
            const int k = (kg << 3) + j;
            const float* rk = rl + (k << 6);
            float4 r0 = *(const float4*)(rk + 0);
            float4 r1 = *(const float4*)(rk + 4);
            float4 r2 = *(const float4*)(rk + 8);
            float4 r3 = *(const float4*)(rk + 12);
            const float hv = hreg[j];
            acc[0]  += hv * r0.x; acc[1]  += hv * r0.y;
            acc[2]  += hv * r0.z; acc[3]  += hv * r0.w;
            acc[4]  += hv * r1.x; acc[5]  += hv * r1.y;
            acc[6]  += hv * r1.z; acc[7]  += hv * r1.w;
            acc[8]  += hv * r2.x; acc[9]  += hv * r2.y;
            acc[10] += hv * r2.z; acc[11] += hv * r2.w;
            acc[12] += hv * r3.x; acc[13] += hv * r3.y;
            acc[14] += hv * r3.z; acc[15] += hv * r3.w;
        }
#pragma unroll
        for (int j = 0; j < 8; j++) hreg[j] = hnxt[j];
    }

    // Epilogue: 4 units per lane. Packed col' j -> unit u0+(j>>2), gate j&3
    // (Keras order i,f,g,o).
    const float wk[16] = { wkA.x, wkA.y, wkA.z, wkA.w,
                           wkB.x, wkB.y, wkB.z, wkB.w,
                           wkC.x, wkC.y, wkC.z, wkC.w,
                           wkD.x, wkD.y, wkD.z, wkD.w };
    const int u0 = (ug << 4) + (w << 2);
#pragma unroll
    for (int q = 0; q < 4; q++) {
        const int u = u0 + q;
        float zi = acc[(q << 2) + 0] + wk[(q << 2) + 0];
        float zf = acc[(q << 2) + 1] + wk[(q << 2) + 1];
        float zg = acc[(q << 2) + 2] + wk[(q << 2) + 2];
        float zo = acc[(q << 2) + 3] + wk[(q << 2) + 3];
        float ig = sigf(zi);
        float fg = sigf(zf);
        float gg = tanhf_(zg);
        float og = sigf(zo);
        const int sidx = (u << 10) + b;
        float c = cT[sidx];
        c = fg * c + ig * gg;
        cT[sidx] = c;
        hout[sidx] = og * tanhf_(c);
    }
}

// ---------------------------------------------------------------------------
// logits = h_last @ dense_w + dense_b ; softmax. h arrives transposed [u][b].
__global__ __launch_bounds__(128) void dense_softmax(
    const float* __restrict__ hT,  // [256][1024]
    const float* __restrict__ W,   // [256][128]
    const float* __restrict__ b,   // [128]
    float*       __restrict__ out) // [1024][128]
{
    __shared__ float hsr[UNITS];
    __shared__ float red[NC];
    const int bq = blockIdx.x;
    const int n  = threadIdx.x;

    hsr[n]       = hT[(n << 10) + bq];
    hsr[n + 128] = hT[((n + 128) << 10) + bq];
    __syncthreads();

    float acc = b[n];
#pragma unroll 8
    for (int k = 0; k < UNITS; k++) acc += hsr[k] * W[k * NC + n];

    red[n] = acc;
    __syncthreads();
    for (int s = 64; s > 0; s >>= 1) {
        if (n < s) red[n] = fmaxf(red[n], red[n + s]);
        __syncthreads();
    }
    float m = red[0];
    __syncthreads();

    float e = __expf(acc - m);
    red[n] = e;
    __syncthreads();
    for (int s = 64; s > 0; s >>= 1) {
        if (n < s) red[n] = red[n] + red[n + s];
        __syncthreads();
    }
    out[bq * NC + n] = e / red[0];
}

// ---------------------------------------------------------------------------
extern "C" void kernel_launch(void* const* d_in, const int* in_sizes, int n_in,
                              void* d_out, int out_size, void* d_ws, size_t ws_size,
                              hipStream_t stream)
{
    const int*   inp  = (const int*)d_in[0];    // [1024][256]
    const float* Wk   = (const float*)d_in[1];  // [128][1024]
    const float* R    = (const float*)d_in[2];  // [256][1024]
    const float* bias = (const float*)d_in[3];  // [1024]
    const float* Wd   = (const float*)d_in[4];  // [256][128]
    const float* bd   = (const float*)d_in[5];  // [128]
    float* out = (float*)d_out;

    // ws layout (floats): hTA | hTB | Rp | cT | Wkb  = 4.72 MB
    float* hTA = (float*)d_ws;
    float* hTB = hTA + 262144;
    float* Rp  = hTB + 262144;
    float* cT  = Rp  + 262144;
    float* Wkb = cT  + 262144;

    prep<<<dim3(1024), dim3(256), 0, stream>>>(R, Wk, bias, Rp, Wkb, hTA, cT);

    for (int t = 0; t < SEQ; t++) {
        const float* hin  = (t & 1) ? hTB : hTA;
        float*       hout = (t & 1) ? hTA : hTB;
        lstm_step<<<dim3(256), dim3(256), 0, stream>>>(hin, hout, cT, Rp, Wkb, inp, t);
    }
    // t=255 (odd) wrote hTA
    dense_softmax<<<dim3(BATCH), dim3(128), 0, stream>>>(hTA, Wd, bd, out);
}

// Round 4
// 2977.942 us; speedup vs baseline: 3.1232x; 1.4450x over previous
//
#include <hip/hip_runtime.h>
#include <math.h>

#define BATCH 1024
#define SEQ   256
#define UNITS 256
#define NC    128

typedef __attribute__((ext_vector_type(8))) short   short8;   // 8 bf16 = 4 VGPRs
typedef __attribute__((ext_vector_type(4))) float   float4v;  // MFMA C/D

// Gate math (validated r1-r3: absmax 6.1e-5 vs 1.72e-4 threshold)
__device__ __forceinline__ float sigf(float x)  { return 1.f / (1.f + __expf(-x)); }
__device__ __forceinline__ float tanhf_(float x){ return 1.f - 2.f / (1.f + __expf(2.f * x)); }

__device__ __forceinline__ unsigned short bf16rne(float f) {
    unsigned u = __float_as_uint(f);
    return (unsigned short)((u + 0x7fffu + ((u >> 16) & 1u)) >> 16);
}
__device__ __forceinline__ float bf16tof(unsigned short s) {
    return __uint_as_float(((unsigned)s) << 16);
}

// ---------------------------------------------------------------------------
// prep: R[k][col] -> R0t/R1t[col][k] bf16 split (col = g*256+u, done once);
//       Wkb[ch][u*4+g] = Wk[ch][g*256+u] + bias  (gate-packed float4 gather);
//       zero H0A/H1A (h_0 = 0) and cT (c_0 = 0).
__global__ __launch_bounds__(256) void prep(
    const float* __restrict__ R, const float* __restrict__ Wk,
    const float* __restrict__ bias,
    unsigned short* __restrict__ R0t, unsigned short* __restrict__ R1t,
    float* __restrict__ Wkb,
    unsigned short* __restrict__ H0A, unsigned short* __restrict__ H1A,
    float* __restrict__ cT)
{
    int i = blockIdx.x * 256 + threadIdx.x;    // 0..262143
    int col = i >> 8, k = i & 255;
    float v = R[k * 1024 + col];
    unsigned short r0 = bf16rne(v);
    unsigned short r1 = bf16rne(v - bf16tof(r0));
    R0t[i] = r0;  R1t[i] = r1;
    H0A[i] = 0;   H1A[i] = 0;
    cT[i] = 0.f;
    if (i < NC * 1024) {
        int r = i & 1023;
        int u = r >> 2, g = r & 3;
        int src = (g << 8) + u;
        Wkb[i] = Wk[(i >> 10) * 1024 + src] + bias[src];
    }
}

// ---------------------------------------------------------------------------
// One timestep via split-bf16 MFMA. Grid 256 blocks x 256 thr (4 waves).
// Block = 64 batches x 16 units; wave w = m-tile (16 batches) x 4 gate-plane
// C-tiles (16 units each). Lane: unit = uu+(lane&15); batches = bm+quad*4+r.
// Fragment layouts (m89/m120-verified):
//   A[m=lane&15][k=quad*8+j]  <- H[b][k] row-major, 16B contiguous
//   B[k=quad*8+j][n=lane&15]  <- Rt[col][k] row-major, 16B contiguous
//   D col=lane&15, row=quad*4+reg
__global__ __launch_bounds__(256) void lstm_step(
    const unsigned short* __restrict__ H0in, const unsigned short* __restrict__ H1in,
    unsigned short* __restrict__ H0out, unsigned short* __restrict__ H1out,
    float* __restrict__ cT,
    const unsigned short* __restrict__ R0t, const unsigned short* __restrict__ R1t,
    const float* __restrict__ Wkb, const int* __restrict__ inp, int t)
{
    const int tid  = threadIdx.x;
    const int lane = tid & 63;
    const int w    = tid >> 6;
    const int bt   = blockIdx.x & 15;
    const int ut   = blockIdx.x >> 4;
    const int nl   = lane & 15;
    const int quad = lane >> 4;
    const int bm   = (bt << 6) + (w << 4);   // wave's 16-batch base
    const int uu   = ut << 4;
    const int u    = uu + nl;                // lane's unit
    const int be   = bm + (quad << 2);       // lane's 4-batch base

    // Epilogue gathers, issued before the MFMA loop to overlap.
    const int ch0 = inp[(be + 0) * SEQ + t];
    const int ch1 = inp[(be + 1) * SEQ + t];
    const int ch2 = inp[(be + 2) * SEQ + t];
    const int ch3 = inp[(be + 3) * SEQ + t];
    float4v wk0 = *(const float4v*)&Wkb[(ch0 << 10) + (u << 2)];
    float4v wk1 = *(const float4v*)&Wkb[(ch1 << 10) + (u << 2)];
    float4v wk2 = *(const float4v*)&Wkb[(ch2 << 10) + (u << 2)];
    float4v wk3 = *(const float4v*)&Wkb[(ch3 << 10) + (u << 2)];

    float4v acc0 = {0.f, 0.f, 0.f, 0.f};
    float4v acc1 = acc0, acc2 = acc0, acc3 = acc0;

    const unsigned short* ha0 = H0in + (bm + nl) * 256 + (quad << 3);
    const unsigned short* ha1 = H1in + (bm + nl) * 256 + (quad << 3);
    const unsigned short* rb0 = R0t + u * 256 + (quad << 3);  // + g*65536 + kt*32
    const unsigned short* rb1 = R1t + u * 256 + (quad << 3);

#pragma unroll
    for (int kt = 0; kt < 8; kt++) {
        short8 a0 = *(const short8*)(ha0 + kt * 32);
        short8 a1 = *(const short8*)(ha1 + kt * 32);
#define GATE(G, ACC)                                                          \
        {                                                                     \
            short8 b0 = *(const short8*)(rb0 + (G) * 65536 + kt * 32);        \
            short8 b1 = *(const short8*)(rb1 + (G) * 65536 + kt * 32);        \
            ACC = __builtin_amdgcn_mfma_f32_16x16x32_bf16(a0, b0, ACC, 0, 0, 0); \
            ACC = __builtin_amdgcn_mfma_f32_16x16x32_bf16(a1, b0, ACC, 0, 0, 0); \
            ACC = __builtin_amdgcn_mfma_f32_16x16x32_bf16(a0, b1, ACC, 0, 0, 0); \
            ACC = __builtin_amdgcn_mfma_f32_16x16x32_bf16(a1, b1, ACC, 0, 0, 0); \
        }
        GATE(0, acc0) GATE(1, acc1) GATE(2, acc2) GATE(3, acc3)
#undef GATE
    }

    // Epilogue: lane holds z (minus xproj) for 4 batches x 1 unit x 4 gates.
    float4v cv = *(float4v*)&cT[(u << 10) + be];
    float4v wks[4] = {wk0, wk1, wk2, wk3};
    float hv[4];
#pragma unroll
    for (int r = 0; r < 4; r++) {
        float zi = acc0[r] + wks[r].x;
        float zf = acc1[r] + wks[r].y;
        float zg = acc2[r] + wks[r].z;
        float zo = acc3[r] + wks[r].w;
        float ig = sigf(zi), fg = sigf(zf), gg = tanhf_(zg), og = sigf(zo);
        float c  = fg * cv[r] + ig * gg;
        cv[r] = c;
        hv[r] = og * tanhf_(c);
    }
    *(float4v*)&cT[(u << 10) + be] = cv;
#pragma unroll
    for (int r = 0; r < 4; r++) {
        unsigned short h0 = bf16rne(hv[r]);
        unsigned short h1 = bf16rne(hv[r] - bf16tof(h0));
        H0out[(be + r) * 256 + u] = h0;
        H1out[(be + r) * 256 + u] = h1;
    }
}

// ---------------------------------------------------------------------------
// logits = h_last @ dense_w + dense_b ; softmax. h reconstructed = h0 + h1.
__global__ __launch_bounds__(128) void dense_softmax(
    const unsigned short* __restrict__ H0, const unsigned short* __restrict__ H1,
    const float* __restrict__ W, const float* __restrict__ b,
    float* __restrict__ out)
{
    __shared__ float hsr[UNITS];
    __shared__ float red[NC];
    const int bq = blockIdx.x;
    const int n  = threadIdx.x;

    hsr[n]       = bf16tof(H0[bq * 256 + n])       + bf16tof(H1[bq * 256 + n]);
    hsr[n + 128] = bf16tof(H0[bq * 256 + n + 128]) + bf16tof(H1[bq * 256 + n + 128]);
    __syncthreads();

    float acc = b[n];
#pragma unroll 8
    for (int k = 0; k < UNITS; k++) acc += hsr[k] * W[k * NC + n];

    red[n] = acc;
    __syncthreads();
    for (int s = 64; s > 0; s >>= 1) {
        if (n < s) red[n] = fmaxf(red[n], red[n + s]);
        __syncthreads();
    }
    float m = red[0];
    __syncthreads();

    float e = __expf(acc - m);
    red[n] = e;
    __syncthreads();
    for (int s = 64; s > 0; s >>= 1) {
        if (n < s) red[n] = red[n] + red[n + s];
        __syncthreads();
    }
    out[bq * NC + n] = e / red[0];
}

// ---------------------------------------------------------------------------
extern "C" void kernel_launch(void* const* d_in, const int* in_sizes, int n_in,
                              void* d_out, int out_size, void* d_ws, size_t ws_size,
                              hipStream_t stream)
{
    const int*   inp  = (const int*)d_in[0];    // [1024][256]
    const float* Wk   = (const float*)d_in[1];  // [128][1024]
    const float* R    = (const float*)d_in[2];  // [256][1024]
    const float* bias = (const float*)d_in[3];  // [1024]
    const float* Wd   = (const float*)d_in[4];  // [256][128]
    const float* bd   = (const float*)d_in[5];  // [128]
    float* out = (float*)d_out;

    // ws layout: cT (1MB f32) | Wkb (512KB f32) | 6 x ushort[262144] (512KB ea)
    float* cT  = (float*)d_ws;
    float* Wkb = cT + 262144;
    unsigned short* R0t = (unsigned short*)(Wkb + 131072);
    unsigned short* R1t = R0t + 262144;
    unsigned short* H0A = R1t + 262144;
    unsigned short* H1A = H0A + 262144;
    unsigned short* H0B = H1A + 262144;
    unsigned short* H1B = H0B + 262144;

    prep<<<dim3(1024), dim3(256), 0, stream>>>(R, Wk, bias, R0t, R1t, Wkb, H0A, H1A, cT);

    for (int t = 0; t < SEQ; t++) {
        const unsigned short* h0i = (t & 1) ? H0B : H0A;
        const unsigned short* h1i = (t & 1) ? H1B : H1A;
        unsigned short* h0o = (t & 1) ? H0A : H0B;
        unsigned short* h1o = (t & 1) ? H1A : H1B;
        lstm_step<<<dim3(256), dim3(256), 0, stream>>>(h0i, h1i, h0o, h1o, cT,
                                                       R0t, R1t, Wkb, inp, t);
    }
    // t=255 (odd) wrote the A set
    dense_softmax<<<dim3(BATCH), dim3(128), 0, stream>>>(H0A, H1A, Wd, bd, out);
}